// Round 13
// baseline (363.904 us; speedup 1.0000x reference)
//
#include <hip/hip_runtime.h>

#define NN 50000
#define NE 400000
#define NG 64
#define D 256
#define DOUT 16

typedef __attribute__((ext_vector_type(8))) _Float16 f16x8;
typedef __attribute__((ext_vector_type(8))) unsigned short u16x8;
typedef __attribute__((ext_vector_type(4))) float f32x4;

__device__ __forceinline__ unsigned short f2h(float x) {
    union { _Float16 h; unsigned short u; } v;
    v.h = (_Float16)x;                // RNE
    return v.u;
}
__device__ __forceinline__ float h2f(unsigned short u) {
    union { _Float16 h; unsigned short u; } v;
    v.u = u;
    return (float)v.h;
}

// async global->LDS 16B copy (dest = wave-uniform base + lane*16)
__device__ __forceinline__ void async_cp16(void* lds, const void* g) {
    __builtin_amdgcn_global_load_lds(
        (const __attribute__((address_space(1))) unsigned int*)g,
        (__attribute__((address_space(3))) unsigned int*)lds, 16, 0, 0);
}

// ---------------- init: zero cnt + zero pooled + per-graph inv counts ------

__global__ void k_init(int* __restrict__ cnt, float* __restrict__ pooled,
                       const int* __restrict__ batch, float* __restrict__ inv_cnt,
                       int n) {
    int i = blockIdx.x * 256 + threadIdx.x;
    if (i < n) cnt[i] = 0;
    if (i < NG * D) pooled[i] = 0.f;
    if (blockIdx.x == 0 && threadIdx.x < NG) {
        int g = threadIdx.x;
        int lo = 0, hi = n;
        while (lo < hi) { int mid = (lo + hi) >> 1; if (batch[mid] < g) lo = mid + 1; else hi = mid; }
        int start = lo;
        hi = n;
        while (lo < hi) { int mid = (lo + hi) >> 1; if (batch[mid] < g + 1) lo = mid + 1; else hi = mid; }
        inv_cnt[g] = 1.f / fmaxf((float)(lo - start), 1.f);
    }
}

// ---------------- fused: x->f16 + 3x W^T f16 convert + edge count ----------

__global__ void k_split_count(const float* __restrict__ x, unsigned short* __restrict__ ahi,
                              int total4, int xblocks,
                              const float* __restrict__ W1, short* __restrict__ w1h,
                              const float* __restrict__ W2, short* __restrict__ w2h,
                              const float* __restrict__ W3, short* __restrict__ w3h,
                              const int* __restrict__ eidx, int* __restrict__ cnt, int E) {
    int b = blockIdx.x;
    if (b < xblocks) {
        int i = b * 256 + threadIdx.x;
        if (i >= total4) return;
        float4 v = ((const float4*)x)[i];
        ushort4 h;
        h.x = f2h(v.x);
        h.y = f2h(v.y);
        h.z = f2h(v.z);
        h.w = f2h(v.w);
        ((ushort4*)ahi)[i] = h;
    } else if (b < xblocks + 3 * 256) {
        int wb = b - xblocks;
        int which = wb >> 8;               // 0..2
        int idx = (wb & 255) * 256 + threadIdx.x;   // idx = n*256 + k
        int nn = idx >> 8, k = idx & 255;
        const float* W = (which == 0) ? W1 : (which == 1) ? W2 : W3;
        short* Wh = (which == 0) ? w1h : (which == 1) ? w2h : w3h;
        Wh[idx] = (short)f2h(W[k * 256 + nn]);
    } else {
        int e = (b - xblocks - 3 * 256) * 256 + threadIdx.x;
        if (e < E) atomicAdd(&cnt[eidx[E + e]], 1);
    }
}

// exclusive scan of cnt[n] -> excl[n] (+ dinv from final counts), 1024 elems/block
__global__ void k_scan1(const int* __restrict__ cnt, int* __restrict__ excl,
                        int* __restrict__ bsums, float* __restrict__ dinv, int n) {
    __shared__ int sh[256];
    int tid = threadIdx.x;
    int base = blockIdx.x * 1024;
    int v[4]; int tsum = 0;
    for (int j = 0; j < 4; ++j) {
        int i = base + tid * 4 + j;
        v[j] = (i < n) ? cnt[i] : 0;
        if (i < n) dinv[i] = rsqrtf((float)(v[j] + 1));  // +1 self-loop
        tsum += v[j];
    }
    sh[tid] = tsum; __syncthreads();
    for (int d = 1; d < 256; d <<= 1) {
        int t = (tid >= d) ? sh[tid - d] : 0;
        __syncthreads();
        sh[tid] += t;
        __syncthreads();
    }
    int run = sh[tid] - tsum;  // exclusive offset within block
    for (int j = 0; j < 4; ++j) {
        int i = base + tid * 4 + j;
        if (i < n) excl[i] = run;
        run += v[j];
    }
    if (tid == 255) bsums[blockIdx.x] = sh[255];
}

// add bsums-prefix (computed in-wave per block) -> row_ptr, cursor
__global__ void k_scan3(int* __restrict__ row_ptr, const int* __restrict__ bsums,
                        int* __restrict__ cursor, int n, int E, int nb) {
    __shared__ int off_s;
    int chunk = (int)(blockIdx.x >> 2);   // block covers 256 idxs, 4 blocks per 1024-chunk
    if (threadIdx.x < 64) {
        int v = ((int)threadIdx.x < nb && (int)threadIdx.x < chunk) ? bsums[threadIdx.x] : 0;
        #pragma unroll
        for (int d = 1; d < 64; d <<= 1) v += __shfl_xor(v, d);
        if (threadIdx.x == 0) off_s = v;
    }
    __syncthreads();
    int off = off_s;
    int i = blockIdx.x * 256 + threadIdx.x;
    if (i < n) {
        int v = row_ptr[i] + off;
        row_ptr[i] = v;
        cursor[i] = v;
    }
    if (i == 0) row_ptr[n] = E;
}

// ---------------- CSR fill: standalone (gemm runs at 1 block/CU now) -------

__global__ void k_fill(const int* __restrict__ eidx, int* __restrict__ cursor,
                       int* __restrict__ col_src, int E) {
    int e = blockIdx.x * 256 + threadIdx.x;
    if (e < E) {
        int d = eidx[E + e];
        int pos = atomicAdd(&cursor[d], 1);
        col_src[pos] = eidx[e];
    }
}

// ---------------- GEMM body: 224x256 tile, BK=64, global_load_lds staging --
// ONE BLOCK PER CU: grid = ceil(50000/224) = 224 <= 256 CUs. Rationale: gemm
// duration has been ~(max blocks/CU) x block-time across 5 structures (R12:
// 391 blocks -> 135 CUs serialize 2 -> 2x21us = 42). 224 blocks kills the
// ceil-quantization term AND amortizes the fixed 4-per-k-step vmcnt drains
// over 3.5x more work. LDS 60KB, bounds(256,1), acc 224 VGPR/lane (fits 512
// at 1 wave/SIMD). Same staging/swizzle/frag formulas as champion; 4 waves
// in 2x2: wm row-half (112 rows = 7 frags), wn col-half (128 = 8 frags).
// LDS row = 64 shorts; slot (r, chunk c) holds k-chunk q = c ^ ((r>>1)&7),
// folded into the global source address. Second k-half frag = first ^ 32.

__device__ __forceinline__ void gemm_body(
        const unsigned short* __restrict__ A,
        const short* __restrict__ Wh,
        const float* __restrict__ dinv, unsigned short* __restrict__ C, int M,
        int bm, short* Ah_s, short* Bh_s) {
    const int tid = threadIdx.x;
    const int lane = tid & 63;
    const int w    = tid >> 6;
    const int wm   = w & 1;        // wave row half (0-1): 112 rows
    const int wn   = w >> 1;       // wave col half (0-1): 128 cols
    const int lm   = lane & 15;
    const int quad = lane >> 4;

    const int srow = tid >> 3, c = tid & 7;
    const unsigned short* pa[7];
    #pragma unroll
    for (int j = 0; j < 7; ++j) {
        int r = j * 32 + srow;                    // A row 0..223
        int ga = bm + r; if (ga >= M) ga = M - 1;
        int q = c ^ ((r >> 1) & 7);
        pa[j] = A + ((size_t)ga << 8) + q * 8;
    }
    const short* pbh[8];
    #pragma unroll
    for (int j = 0; j < 8; ++j) {
        int r = j * 32 + srow;
        int q = c ^ ((r >> 1) & 7);
        pbh[j] = Wh + ((size_t)r << 8) + q * 8;
    }

    int st[8];
    #pragma unroll
    for (int j = 0; j < 8; ++j) st[j] = j * 2048 + w * 512;

    int oa[7], ob[8];
    #pragma unroll
    for (int i = 0; i < 7; ++i) {
        int ra = wm * 112 + i * 16 + lm;
        oa[i] = ra * 64 + ((quad ^ ((ra >> 1) & 7)) * 8);
    }
    #pragma unroll
    for (int i = 0; i < 8; ++i) {
        int rb = wn * 128 + i * 16 + lm;
        ob[i] = rb * 64 + ((quad ^ ((rb >> 1) & 7)) * 8);
    }

    f32x4 acc[7][8];
    #pragma unroll
    for (int i = 0; i < 7; ++i)
        #pragma unroll
        for (int j = 0; j < 8; ++j)
            acc[i][j] = (f32x4){0.f, 0.f, 0.f, 0.f};

    for (int k0 = 0; k0 < D; k0 += 64) {
        #pragma unroll
        for (int j = 0; j < 7; ++j) async_cp16(&Ah_s[st[j]], pa[j] + k0);
        #pragma unroll
        for (int j = 0; j < 8; ++j) async_cp16(&Bh_s[st[j]], pbh[j] + k0);
        __syncthreads();

        #pragma unroll
        for (int kh = 0; kh < 2; ++kh) {
            const int xo = kh * 32;
            f16x8 Ah[7], Bh[8];
            #pragma unroll
            for (int i = 0; i < 7; ++i) Ah[i] = *(const f16x8*)&Ah_s[oa[i] ^ xo];
            #pragma unroll
            for (int i = 0; i < 8; ++i) Bh[i] = *(const f16x8*)&Bh_s[ob[i] ^ xo];
            #pragma unroll
            for (int mi = 0; mi < 7; ++mi)
                #pragma unroll
                for (int ni = 0; ni < 8; ++ni)
                    acc[mi][ni] = __builtin_amdgcn_mfma_f32_16x16x32_f16(Ah[mi], Bh[ni], acc[mi][ni], 0, 0, 0);
        }
        __syncthreads();
    }

    #pragma unroll
    for (int mi = 0; mi < 7; ++mi) {
        int rbase = bm + wm * 112 + mi * 16 + quad * 4;
        #pragma unroll
        for (int r = 0; r < 4; ++r) {
            int grow = rbase + r;
            if (grow < M) {
                float s = dinv[grow];
                #pragma unroll
                for (int ni = 0; ni < 8; ++ni) {
                    int col = wn * 128 + ni * 16 + lm;
                    C[(size_t)grow * D + col] = f2h(acc[mi][ni][r] * s);
                }
            }
        }
    }
}

// all 3 layers: plain GEMM. 224 blocks, 1/CU, LDS 60KB.
__global__ __launch_bounds__(256, 1) void k_gemm_mfma(
        const unsigned short* __restrict__ A,
        const short* __restrict__ Wh,
        const float* __restrict__ dinv, unsigned short* __restrict__ C, int M) {
    __shared__ short Ah_s[14336];   // 28 KB (224 rows x 64 shorts)
    __shared__ short Bh_s[16384];   // 32 KB
    gemm_body(A, Wh, dinv, C, M, blockIdx.x * 224, Ah_s, Bh_s);
}

// ---------------- aggregation: out = relu(dinv*(h'[d] + sum h'[src]) + b) ----
// One node per wave (R5-proven inner loop), 128-thread blocks (2 waves,
// 2 nodes): block resources retire at max(2 degrees) not max(4) -- the R8
// champion configuration. Per wave: 2 edges per load instruction (lanes
// 0-31 edge j, lanes 32-63 edge j+1; ushort8 = 16B/lane); 8 loads in
// flight; cross-half fold via __shfl_xor(32).

__global__ __launch_bounds__(128) void k_agg(
        const unsigned short* __restrict__ h, const float* __restrict__ dinv,
        const int* __restrict__ row_ptr, const int* __restrict__ col_src,
        const float* __restrict__ bias,
        unsigned short* __restrict__ ohi, int n) {
    int w = threadIdx.x >> 6, lane = threadIdx.x & 63;
    int node = blockIdx.x * 2 + w;
    if (node >= n) return;
    int half = lane >> 5;          // 0: even edges, 1: odd edges
    int dcol = lane & 31;          // owns dims dcol*8 .. dcol*8+7

    float acc[8] = {0.f, 0.f, 0.f, 0.f, 0.f, 0.f, 0.f, 0.f};
    if (half == 0) {               // self-loop on half 0 only
        u16x8 sv = ((const u16x8*)(h + (size_t)node * D))[dcol];
        #pragma unroll
        for (int d = 0; d < 8; ++d) acc[d] = h2f(sv[d]);
    }

    int beg = row_ptr[node], end = row_ptr[node + 1];
    for (int c = beg; c < end; c += 64) {
        int cnt = min(64, end - c);                        // wave-uniform
        int myidx = (lane < cnt) ? col_src[c + lane] : 0;  // coalesced index load
        for (int e = 0; e < cnt; e += 16) {                // 8 instrs x 2 edges
            u16x8 u[8];
            bool val[8];
            #pragma unroll
            for (int j = 0; j < 8; ++j) {
                int eid = e + j * 2 + half;
                val[j] = eid < cnt;
                if (val[j]) {
                    int s = __shfl(myidx, eid);            // per-lane pull
                    u[j] = ((const u16x8*)(h + (size_t)s * D))[dcol];
                }
            }
            #pragma unroll
            for (int j = 0; j < 8; ++j)
                if (val[j]) {
                    #pragma unroll
                    for (int d = 0; d < 8; ++d) acc[d] += h2f(u[j][d]);
                }
        }
    }

    // fold halves: lane L += lane L^32
    #pragma unroll
    for (int d = 0; d < 8; ++d) acc[d] += __shfl_xor(acc[d], 32);

    if (half == 0) {
        float di = dinv[node];
        float4 b0 = ((const float4*)bias)[dcol * 2];
        float4 b1 = ((const float4*)bias)[dcol * 2 + 1];
        float bb[8] = {b0.x, b0.y, b0.z, b0.w, b1.x, b1.y, b1.z, b1.w};
        u16x8 o;
        #pragma unroll
        for (int d = 0; d < 8; ++d)
            o[d] = f2h(fmaxf(acc[d] * di + bb[d], 0.f));
        ((u16x8*)(ohi + (size_t)node * D))[dcol] = o;
    }
}

// ---------------- mean pool: chunked sums + atomic flush -------------------

__global__ __launch_bounds__(256) void k_pool_sum(
        const unsigned short* __restrict__ hi,
        const int* __restrict__ batch, float* __restrict__ pooled, int n) {
    int beg = blockIdx.x * 64;
    if (beg >= n) return;
    int end = min(beg + 64, n);
    int t = threadIdx.x;  // dim t
    float acc = 0.f;
    int cur = batch[beg];
    for (int i = beg; i < end; ++i) {
        int g = batch[i];
        if (g != cur) {
            atomicAdd(&pooled[cur * D + t], acc);
            acc = 0.f;
            cur = g;
        }
        acc += h2f(hi[(size_t)i * D + t]);
    }
    atomicAdd(&pooled[cur * D + t], acc);
}

// ---------------- final FC ----------------

__global__ void k_fc(const float* __restrict__ pooled, const float* __restrict__ inv_cnt,
                     const float* __restrict__ W, const float* __restrict__ b,
                     float* __restrict__ out) {
    int t = blockIdx.x * blockDim.x + threadIdx.x;
    if (t >= NG * DOUT) return;
    int g = t >> 4, o = t & 15;
    float acc = 0.f;
    for (int k = 0; k < D; ++k) acc += pooled[g * D + k] * W[k * DOUT + o];
    out[t] = acc * inv_cnt[g] + b[o];
}

// ---------------- launch ----------------

extern "C" void kernel_launch(void* const* d_in, const int* in_sizes, int n_in,
                              void* d_out, int out_size, void* d_ws, size_t ws_size,
                              hipStream_t stream) {
    const float* x    = (const float*)d_in[0];
    const int*   eidx = (const int*)d_in[1];
    const int*   batch= (const int*)d_in[2];
    const float* W1   = (const float*)d_in[3];
    const float* b1   = (const float*)d_in[4];
    const float* W2   = (const float*)d_in[5];
    const float* b2   = (const float*)d_in[6];
    const float* W3   = (const float*)d_in[7];
    const float* b3   = (const float*)d_in[8];
    const float* Wfc  = (const float*)d_in[9];
    const float* bfc  = (const float*)d_in[10];
    float* out = (float*)d_out;

    const int n = in_sizes[0] / D;      // 50000
    const int E = in_sizes[1] / 2;      // 400000

    // workspace layout (256B aligned slabs)
    char* p = (char*)d_ws;
    auto take = [&](size_t bytes) -> void* {
        void* q = (void*)p;
        p += (bytes + 255) & ~(size_t)255;
        return q;
    };
    int*   cnt     = (int*)take((size_t)n * 4);
    int*   row_ptr = (int*)take((size_t)(n + 1) * 4);
    int*   cursor  = (int*)take((size_t)n * 4);
    int*   col_src = (int*)take((size_t)E * 4);
    int*   bsums   = (int*)take(256 * 4);
    float* dinv    = (float*)take((size_t)n * 4);
    float* inv_cnt = (float*)take((size_t)NG * 4);
    short* w1h     = (short*)take((size_t)D * D * 2);
    short* w2h     = (short*)take((size_t)D * D * 2);
    short* w3h     = (short*)take((size_t)D * D * 2);
    unsigned short* hbuf = (unsigned short*)take((size_t)n * D * 2);  // f16 h'
    unsigned short* ahi  = (unsigned short*)take((size_t)n * D * 2);  // f16 A
    float* pooled  = (float*)take((size_t)NG * D * 4);

    int tb = 256;
    int gn = (n + tb - 1) / tb;
    int ge = (E + tb - 1) / tb;
    int nb = (n + 1023) / 1024;   // 49 scan blocks
    int total4 = n * D / 4;
    int xblocks = (total4 + 255) / 256;

    k_init<<<gn, tb, 0, stream>>>(cnt, pooled, batch, inv_cnt, n);
    k_split_count<<<xblocks + 3 * 256 + ge, tb, 0, stream>>>(
        x, ahi, total4, xblocks,
        W1, w1h, W2, w2h, W3, w3h,
        eidx, cnt, E);
    k_scan1<<<nb, 256, 0, stream>>>(cnt, row_ptr, bsums, dinv, n);
    k_scan3<<<gn, tb, 0, stream>>>(row_ptr, bsums, cursor, n, E, nb);

    int ggrid = (n + 223) / 224;  // 224 blocks -> 1 per CU
    int agrid = (n + 1) / 2;      // 1 node per wave, 2 waves per block

    // CSR fill standalone (gemm is bounds(256,1) -- fusing would throttle fill)
    k_fill<<<ge, tb, 0, stream>>>(eidx, cursor, col_src, E);

    k_gemm_mfma<<<ggrid, 256, 0, stream>>>(ahi, w1h, dinv, hbuf, n);
    k_agg<<<agrid, 128, 0, stream>>>(hbuf, dinv, row_ptr, col_src, b1, ahi, n);

    k_gemm_mfma<<<ggrid, 256, 0, stream>>>(ahi, w2h, dinv, hbuf, n);
    k_agg<<<agrid, 128, 0, stream>>>(hbuf, dinv, row_ptr, col_src, b2, ahi, n);

    k_gemm_mfma<<<ggrid, 256, 0, stream>>>(ahi, w3h, dinv, hbuf, n);
    k_agg<<<agrid, 128, 0, stream>>>(hbuf, dinv, row_ptr, col_src, b3, ahi, n);

    k_pool_sum<<<(n + 63) / 64, 256, 0, stream>>>(ahi, batch, pooled, n);
    k_fc<<<4, 256, 0, stream>>>(pooled, inv_cnt, Wfc, bfc, out);
}

// Round 14
// 346.177 us; speedup vs baseline: 1.0512x; 1.0512x over previous
//
#include <hip/hip_runtime.h>

#define NN 50000
#define NE 400000
#define NG 64
#define D 256
#define DOUT 16

typedef __attribute__((ext_vector_type(8))) _Float16 f16x8;
typedef __attribute__((ext_vector_type(8))) unsigned short u16x8;
typedef __attribute__((ext_vector_type(4))) float f32x4;

__device__ __forceinline__ unsigned short f2h(float x) {
    union { _Float16 h; unsigned short u; } v;
    v.h = (_Float16)x;                // RNE
    return v.u;
}
__device__ __forceinline__ float h2f(unsigned short u) {
    union { _Float16 h; unsigned short u; } v;
    v.u = u;
    return (float)v.h;
}

// async global->LDS 16B copy (dest = wave-uniform base + lane*16)
__device__ __forceinline__ void async_cp16(void* lds, const void* g) {
    __builtin_amdgcn_global_load_lds(
        (const __attribute__((address_space(1))) unsigned int*)g,
        (__attribute__((address_space(3))) unsigned int*)lds, 16, 0, 0);
}

// ---------------- fused: x->f16 + 3x W^T f16 convert + edge count ----------
// (cnt zeroed by hipMemsetAsync before this kernel.)

__global__ void k_split_count(const float* __restrict__ x, unsigned short* __restrict__ ahi,
                              int total4, int xblocks,
                              const float* __restrict__ W1, short* __restrict__ w1h,
                              const float* __restrict__ W2, short* __restrict__ w2h,
                              const float* __restrict__ W3, short* __restrict__ w3h,
                              const int* __restrict__ eidx, int* __restrict__ cnt, int E) {
    int b = blockIdx.x;
    if (b < xblocks) {
        int i = b * 256 + threadIdx.x;
        if (i >= total4) return;
        float4 v = ((const float4*)x)[i];
        ushort4 h;
        h.x = f2h(v.x);
        h.y = f2h(v.y);
        h.z = f2h(v.z);
        h.w = f2h(v.w);
        ((ushort4*)ahi)[i] = h;
    } else if (b < xblocks + 3 * 256) {
        int wb = b - xblocks;
        int which = wb >> 8;               // 0..2
        int idx = (wb & 255) * 256 + threadIdx.x;   // idx = n*256 + k
        int nn = idx >> 8, k = idx & 255;
        const float* W = (which == 0) ? W1 : (which == 1) ? W2 : W3;
        short* Wh = (which == 0) ? w1h : (which == 1) ? w2h : w3h;
        Wh[idx] = (short)f2h(W[k * 256 + nn]);
    } else {
        int e = (b - xblocks - 3 * 256) * 256 + threadIdx.x;
        if (e < E) atomicAdd(&cnt[eidx[E + e]], 1);
    }
}

// exclusive scan of cnt[n] -> excl[n] (+ dinv from final counts), 1024 elems/block
__global__ void k_scan1(const int* __restrict__ cnt, int* __restrict__ excl,
                        int* __restrict__ bsums, float* __restrict__ dinv, int n) {
    __shared__ int sh[256];
    int tid = threadIdx.x;
    int base = blockIdx.x * 1024;
    int v[4]; int tsum = 0;
    for (int j = 0; j < 4; ++j) {
        int i = base + tid * 4 + j;
        v[j] = (i < n) ? cnt[i] : 0;
        if (i < n) dinv[i] = rsqrtf((float)(v[j] + 1));  // +1 self-loop
        tsum += v[j];
    }
    sh[tid] = tsum; __syncthreads();
    for (int d = 1; d < 256; d <<= 1) {
        int t = (tid >= d) ? sh[tid - d] : 0;
        __syncthreads();
        sh[tid] += t;
        __syncthreads();
    }
    int run = sh[tid] - tsum;  // exclusive offset within block
    for (int j = 0; j < 4; ++j) {
        int i = base + tid * 4 + j;
        if (i < n) excl[i] = run;
        run += v[j];
    }
    if (tid == 255) bsums[blockIdx.x] = sh[255];
}

// add bsums-prefix (computed in-wave per block) -> row_ptr, cursor
__global__ void k_scan3(int* __restrict__ row_ptr, const int* __restrict__ bsums,
                        int* __restrict__ cursor, int n, int E, int nb) {
    __shared__ int off_s;
    int chunk = (int)(blockIdx.x >> 2);   // block covers 256 idxs, 4 blocks per 1024-chunk
    if (threadIdx.x < 64) {
        int v = ((int)threadIdx.x < nb && (int)threadIdx.x < chunk) ? bsums[threadIdx.x] : 0;
        #pragma unroll
        for (int d = 1; d < 64; d <<= 1) v += __shfl_xor(v, d);
        if (threadIdx.x == 0) off_s = v;
    }
    __syncthreads();
    int off = off_s;
    int i = blockIdx.x * 256 + threadIdx.x;
    if (i < n) {
        int v = row_ptr[i] + off;
        row_ptr[i] = v;
        cursor[i] = v;
    }
    if (i == 0) row_ptr[n] = E;
}

// ---------------- GEMM body: 128x256 tile, BK=64, global_load_lds staging --
// (R12 champion.) A f16 [M][256]; Wt f16 [256 n][256 k]. 4 waves: wm=w&1
// row-half (64 rows), wn=w>>1 col-half (128 cols); acc mi=4 x ni=8. LDS row
// = 64 shorts; slot (r, chunk c) holds k-chunk q = c ^ ((r>>1)&7), folded
// into the global source address. Second k-half frag offset = first ^ 32.

__device__ __forceinline__ void gemm_body(
        const unsigned short* __restrict__ A,
        const short* __restrict__ Wh,
        const float* __restrict__ dinv, unsigned short* __restrict__ C, int M,
        int bm, short* Ah_s, short* Bh_s) {
    const int tid = threadIdx.x;
    const int lane = tid & 63;
    const int w    = tid >> 6;
    const int wm   = w & 1;        // wave row half (0-1): 64 rows
    const int wn   = w >> 1;       // wave col half (0-1): 128 cols
    const int lm   = lane & 15;
    const int quad = lane >> 4;

    const int srow = tid >> 3, c = tid & 7;
    const int q = c ^ ((srow >> 1) & 7);
    const unsigned short* pa[4];
    #pragma unroll
    for (int j = 0; j < 4; ++j) {
        int ga = bm + j * 32 + srow; if (ga >= M) ga = M - 1;
        pa[j] = A + ((size_t)ga << 8) + q * 8;
    }
    const short* pbh[8];
    #pragma unroll
    for (int j = 0; j < 8; ++j)
        pbh[j] = Wh + ((size_t)(j * 32 + srow) << 8) + q * 8;

    int st[8];
    #pragma unroll
    for (int j = 0; j < 8; ++j) st[j] = j * 2048 + w * 512;

    int oa[4], ob[8];
    #pragma unroll
    for (int i = 0; i < 4; ++i) {
        int ra = wm * 64 + i * 16 + lm;
        oa[i] = ra * 64 + ((quad ^ ((ra >> 1) & 7)) * 8);
    }
    #pragma unroll
    for (int i = 0; i < 8; ++i) {
        int rb = wn * 128 + i * 16 + lm;
        ob[i] = rb * 64 + ((quad ^ ((rb >> 1) & 7)) * 8);
    }

    f32x4 acc[4][8];
    #pragma unroll
    for (int i = 0; i < 4; ++i)
        #pragma unroll
        for (int j = 0; j < 8; ++j)
            acc[i][j] = (f32x4){0.f, 0.f, 0.f, 0.f};

    for (int k0 = 0; k0 < D; k0 += 64) {
        #pragma unroll
        for (int j = 0; j < 4; ++j) async_cp16(&Ah_s[st[j]], pa[j] + k0);
        #pragma unroll
        for (int j = 0; j < 8; ++j) async_cp16(&Bh_s[st[j]], pbh[j] + k0);
        __syncthreads();

        #pragma unroll
        for (int kh = 0; kh < 2; ++kh) {
            const int xo = kh * 32;
            f16x8 Ah[4], Bh[8];
            #pragma unroll
            for (int i = 0; i < 4; ++i) Ah[i] = *(const f16x8*)&Ah_s[oa[i] ^ xo];
            #pragma unroll
            for (int i = 0; i < 8; ++i) Bh[i] = *(const f16x8*)&Bh_s[ob[i] ^ xo];
            #pragma unroll
            for (int mi = 0; mi < 4; ++mi)
                #pragma unroll
                for (int ni = 0; ni < 8; ++ni)
                    acc[mi][ni] = __builtin_amdgcn_mfma_f32_16x16x32_f16(Ah[mi], Bh[ni], acc[mi][ni], 0, 0, 0);
        }
        __syncthreads();
    }

    #pragma unroll
    for (int mi = 0; mi < 4; ++mi) {
        int rbase = bm + wm * 64 + mi * 16 + quad * 4;
        #pragma unroll
        for (int r = 0; r < 4; ++r) {
            int grow = rbase + r;
            if (grow < M) {
                float s = dinv[grow];
                #pragma unroll
                for (int ni = 0; ni < 8; ++ni) {
                    int col = wn * 128 + ni * 16 + lm;
                    C[(size_t)grow * D + col] = f2h(acc[mi][ni][r] * s);
                }
            }
        }
    }
}

// layers 2-3: plain GEMM. LDS 48KB; bounds(256,2).
__global__ __launch_bounds__(256, 2) void k_gemm_mfma(
        const unsigned short* __restrict__ A,
        const short* __restrict__ Wh,
        const float* __restrict__ dinv, unsigned short* __restrict__ C, int M) {
    __shared__ short Ah_s[8192];    // 16 KB
    __shared__ short Bh_s[16384];   // 32 KB
    gemm_body(A, Wh, dinv, C, M, blockIdx.x * 128, Ah_s, Bh_s);
}

// layer 1: GEMM + CSR fill fused in one grid (independent work; fill
// overlaps the gemm -- R2/R8-proven win). Blocks [0,gblocks) gemm, rest fill.
__global__ __launch_bounds__(256, 2) void k_gemm1_fill(
        const unsigned short* __restrict__ A,
        const short* __restrict__ Wh,
        const float* __restrict__ dinv, unsigned short* __restrict__ C, int M,
        int gblocks, const int* __restrict__ eidx, int* __restrict__ cursor,
        int* __restrict__ col_src, int E) {
    __shared__ short Ah_s[8192];
    __shared__ short Bh_s[16384];
    if ((int)blockIdx.x < gblocks) {
        gemm_body(A, Wh, dinv, C, M, blockIdx.x * 128, Ah_s, Bh_s);
    } else {
        int e = ((int)blockIdx.x - gblocks) * 256 + threadIdx.x;
        if (e < E) {
            int d = eidx[E + e];
            int pos = atomicAdd(&cursor[d], 1);
            col_src[pos] = eidx[e];
        }
    }
}

// ---------------- aggregation: out = relu(dinv*(h'[d] + sum h'[src]) + b) ----
// One node per wave (R5-proven inner loop), 128-thread blocks (2 waves,
// 2 nodes): block resources retire at max(2 degrees) not max(4) -- the R8
// champion configuration. Per wave: 2 edges per load instruction (lanes
// 0-31 edge j, lanes 32-63 edge j+1; ushort8 = 16B/lane); 8 loads in
// flight; cross-half fold via __shfl_xor(32).

__global__ __launch_bounds__(128) void k_agg(
        const unsigned short* __restrict__ h, const float* __restrict__ dinv,
        const int* __restrict__ row_ptr, const int* __restrict__ col_src,
        const float* __restrict__ bias,
        unsigned short* __restrict__ ohi, int n) {
    int w = threadIdx.x >> 6, lane = threadIdx.x & 63;
    int node = blockIdx.x * 2 + w;
    if (node >= n) return;
    int half = lane >> 5;          // 0: even edges, 1: odd edges
    int dcol = lane & 31;          // owns dims dcol*8 .. dcol*8+7

    float acc[8] = {0.f, 0.f, 0.f, 0.f, 0.f, 0.f, 0.f, 0.f};
    if (half == 0) {               // self-loop on half 0 only
        u16x8 sv = ((const u16x8*)(h + (size_t)node * D))[dcol];
        #pragma unroll
        for (int d = 0; d < 8; ++d) acc[d] = h2f(sv[d]);
    }

    int beg = row_ptr[node], end = row_ptr[node + 1];
    for (int c = beg; c < end; c += 64) {
        int cnt = min(64, end - c);                        // wave-uniform
        int myidx = (lane < cnt) ? col_src[c + lane] : 0;  // coalesced index load
        for (int e = 0; e < cnt; e += 16) {                // 8 instrs x 2 edges
            u16x8 u[8];
            bool val[8];
            #pragma unroll
            for (int j = 0; j < 8; ++j) {
                int eid = e + j * 2 + half;
                val[j] = eid < cnt;
                if (val[j]) {
                    int s = __shfl(myidx, eid);            // per-lane pull
                    u[j] = ((const u16x8*)(h + (size_t)s * D))[dcol];
                }
            }
            #pragma unroll
            for (int j = 0; j < 8; ++j)
                if (val[j]) {
                    #pragma unroll
                    for (int d = 0; d < 8; ++d) acc[d] += h2f(u[j][d]);
                }
        }
    }

    // fold halves: lane L += lane L^32
    #pragma unroll
    for (int d = 0; d < 8; ++d) acc[d] += __shfl_xor(acc[d], 32);

    if (half == 0) {
        float di = dinv[node];
        float4 b0 = ((const float4*)bias)[dcol * 2];
        float4 b1 = ((const float4*)bias)[dcol * 2 + 1];
        float bb[8] = {b0.x, b0.y, b0.z, b0.w, b1.x, b1.y, b1.z, b1.w};
        u16x8 o;
        #pragma unroll
        for (int d = 0; d < 8; ++d)
            o[d] = f2h(fmaxf(acc[d] * di + bb[d], 0.f));
        ((u16x8*)(ohi + (size_t)node * D))[dcol] = o;
    }
}

// ---------------- mean pool: chunked sums + atomic flush -------------------
// (pooled zeroed by hipMemsetAsync at launch start.)

__global__ __launch_bounds__(256) void k_pool_sum(
        const unsigned short* __restrict__ hi,
        const int* __restrict__ batch, float* __restrict__ pooled, int n) {
    int beg = blockIdx.x * 64;
    if (beg >= n) return;
    int end = min(beg + 64, n);
    int t = threadIdx.x;  // dim t
    float acc = 0.f;
    int cur = batch[beg];
    for (int i = beg; i < end; ++i) {
        int g = batch[i];
        if (g != cur) {
            atomicAdd(&pooled[cur * D + t], acc);
            acc = 0.f;
            cur = g;
        }
        acc += h2f(hi[(size_t)i * D + t]);
    }
    atomicAdd(&pooled[cur * D + t], acc);
}

// ---------------- final FC (inv_cnt computed inline: k_init removed) -------

__global__ void k_fc(const float* __restrict__ pooled, const int* __restrict__ batch,
                     int n, const float* __restrict__ W, const float* __restrict__ b,
                     float* __restrict__ out) {
    int t = blockIdx.x * blockDim.x + threadIdx.x;
    if (t >= NG * DOUT) return;
    int g = t >> 4, o = t & 15;
    // per-graph node count via binary search on sorted batch (17 iters x 2)
    int lo = 0, hi = n;
    while (lo < hi) { int mid = (lo + hi) >> 1; if (batch[mid] < g) lo = mid + 1; else hi = mid; }
    int start = lo;
    hi = n;
    while (lo < hi) { int mid = (lo + hi) >> 1; if (batch[mid] < g + 1) lo = mid + 1; else hi = mid; }
    float ic = 1.f / fmaxf((float)(lo - start), 1.f);
    float acc = 0.f;
    for (int k = 0; k < D; ++k) acc += pooled[g * D + k] * W[k * DOUT + o];
    out[t] = acc * ic + b[o];
}

// ---------------- launch ----------------

extern "C" void kernel_launch(void* const* d_in, const int* in_sizes, int n_in,
                              void* d_out, int out_size, void* d_ws, size_t ws_size,
                              hipStream_t stream) {
    const float* x    = (const float*)d_in[0];
    const int*   eidx = (const int*)d_in[1];
    const int*   batch= (const int*)d_in[2];
    const float* W1   = (const float*)d_in[3];
    const float* b1   = (const float*)d_in[4];
    const float* W2   = (const float*)d_in[5];
    const float* b2   = (const float*)d_in[6];
    const float* W3   = (const float*)d_in[7];
    const float* b3   = (const float*)d_in[8];
    const float* Wfc  = (const float*)d_in[9];
    const float* bfc  = (const float*)d_in[10];
    float* out = (float*)d_out;

    const int n = in_sizes[0] / D;      // 50000
    const int E = in_sizes[1] / 2;      // 400000

    // workspace layout (256B aligned slabs)
    char* p = (char*)d_ws;
    auto take = [&](size_t bytes) -> void* {
        void* q = (void*)p;
        p += (bytes + 255) & ~(size_t)255;
        return q;
    };
    int*   cnt     = (int*)take((size_t)n * 4);
    int*   row_ptr = (int*)take((size_t)(n + 1) * 4);
    int*   cursor  = (int*)take((size_t)n * 4);
    int*   col_src = (int*)take((size_t)E * 4);
    int*   bsums   = (int*)take(256 * 4);
    float* dinv    = (float*)take((size_t)n * 4);
    short* w1h     = (short*)take((size_t)D * D * 2);
    short* w2h     = (short*)take((size_t)D * D * 2);
    short* w3h     = (short*)take((size_t)D * D * 2);
    unsigned short* hbuf = (unsigned short*)take((size_t)n * D * 2);  // f16 h'
    unsigned short* ahi  = (unsigned short*)take((size_t)n * D * 2);  // f16 A
    float* pooled  = (float*)take((size_t)NG * D * 4);

    int tb = 256;
    int ge = (E + tb - 1) / tb;
    int nb = (n + 1023) / 1024;   // 49 scan blocks
    int total4 = n * D / 4;
    int xblocks = (total4 + 255) / 256;
    int gn = (n + tb - 1) / tb;

    // zero cnt + pooled (replaces k_init; capture-safe async memsets)
    hipMemsetAsync(cnt, 0, (size_t)n * 4, stream);
    hipMemsetAsync(pooled, 0, (size_t)NG * D * 4, stream);

    k_split_count<<<xblocks + 3 * 256 + ge, tb, 0, stream>>>(
        x, ahi, total4, xblocks,
        W1, w1h, W2, w2h, W3, w3h,
        eidx, cnt, E);
    k_scan1<<<nb, 256, 0, stream>>>(cnt, row_ptr, bsums, dinv, n);
    k_scan3<<<gn, tb, 0, stream>>>(row_ptr, bsums, cursor, n, E, nb);

    int ggrid = (n + 127) / 128;  // 391
    int agrid = (n + 1) / 2;      // 1 node per wave, 2 waves per block

    // layer-1 GEMM fused with CSR fill (independent; fill overlaps gemm)
    k_gemm1_fill<<<ggrid + ge, 256, 0, stream>>>(ahi, w1h, dinv, hbuf, n,
                                                 ggrid, eidx, cursor, col_src, E);
    k_agg<<<agrid, 128, 0, stream>>>(hbuf, dinv, row_ptr, col_src, b1, ahi, n);

    k_gemm_mfma<<<ggrid, 256, 0, stream>>>(ahi, w2h, dinv, hbuf, n);
    k_agg<<<agrid, 128, 0, stream>>>(hbuf, dinv, row_ptr, col_src, b2, ahi, n);

    k_gemm_mfma<<<ggrid, 256, 0, stream>>>(ahi, w3h, dinv, hbuf, n);
    k_agg<<<agrid, 128, 0, stream>>>(hbuf, dinv, row_ptr, col_src, b3, ahi, n);

    k_pool_sum<<<(n + 63) / 64, 256, 0, stream>>>(ahi, batch, pooled, n);
    k_fc<<<4, 256, 0, stream>>>(pooled, batch, n, Wfc, bfc, out);
}